// Round 3
// baseline (841.006 us; speedup 1.0000x reference)
//
#include <hip/hip_runtime.h>

// ---------------------------------------------------------------------------
// HopfieldPooling on MI355X (gfx950)
//   x -> xh/xl planar bf16 (preconversion pass; ws-size guarded)
//   k = x@Wk^T  (split-bf16 MFMA GEMM, 3-term), k stored PACKED (hi|lo<<16)
//   q0 = query@Wq^T (fp32)
//   3x Hopfield steps: split-N attention, fixed shift m=0 (softmax_1), atomics
//   out = (q@Wv^T)@Wproj^T + b  (fp32 vector)
// ---------------------------------------------------------------------------

typedef float  float4v  __attribute__((ext_vector_type(4)));
typedef short  short4v  __attribute__((ext_vector_type(4)));
typedef short  short8v  __attribute__((ext_vector_type(8)));
typedef unsigned int uint4v __attribute__((ext_vector_type(4)));
typedef short8v bf16x8;   // 8 bf16 = 4 VGPRs, MFMA A/B frag

#define NC 8   // n-chunks per (b,h) in attention step

__device__ __forceinline__ unsigned short f2bf_hi(float f){
  unsigned int u = __float_as_uint(f);
  u += 0x7fffu + ((u >> 16) & 1u);            // round-to-nearest-even
  return (unsigned short)(u >> 16);
}
__device__ __forceinline__ float bf2f(unsigned short h){
  return __uint_as_float(((unsigned int)h) << 16);
}
__device__ __forceinline__ unsigned int packbf(float v){
  unsigned short hh = f2bf_hi(v);
  return (unsigned)hh | ((unsigned)f2bf_hi(v - bf2f(hh)) << 16);
}

// ---------------------------------------------------------------------------
// fp32 -> planar hi/lo bf16 (used for Wk 768x768 and for x 16x4096x768)
// ---------------------------------------------------------------------------
__global__ __launch_bounds__(256)
void cvt_planar_kernel(const float* __restrict__ src, unsigned short* __restrict__ dh,
                       unsigned short* __restrict__ dl){
  size_t idx = (size_t)blockIdx.x*256 + threadIdx.x;   // one float4 per thread
  float4v v = ((const float4v*)src)[idx];
  short4v h4, l4;
  #pragma unroll
  for(int e=0;e<4;e++){
    unsigned short hh = f2bf_hi(v[e]);
    h4[e] = (short)hh;
    l4[e] = (short)f2bf_hi(v[e] - bf2f(hh));
  }
  ((short4v*)dh)[idx] = h4;
  ((short4v*)dl)[idx] = l4;
}

// ---------------------------------------------------------------------------
// q0[l][c] = sum_j query[l][j]*Wq[c][j]   (16x768, fp32)
// ---------------------------------------------------------------------------
__global__ __launch_bounds__(256)
void q0_kernel(const float* __restrict__ query, const float* __restrict__ wq,
               float* __restrict__ q0){
  int idx = blockIdx.x*256 + threadIdx.x;     // 12288
  int l = idx / 768, c = idx - l*768;
  const float* qr = query + l*768;
  const float* wr = wq + (size_t)c*768;
  float s = 0.f;
  for(int j=0;j<768;j+=4){
    float4v a  = *(const float4v*)(qr+j);
    float4v w4 = *(const float4v*)(wr+j);
    s += a[0]*w4[0]+a[1]*w4[1]+a[2]*w4[2]+a[3]*w4[3];
  }
  q0[idx] = s;
}

// ---------------------------------------------------------------------------
// k = x @ Wk^T, preconverted-x variant. M=65536, N=768, K=768.
// 128x128 tile, BK=32, 4 waves. Output k packed (hi | lo<<16).
// Grid: (bn=6, bm=512) -> same-bm blocks adjacent for x-tile L2/L3 reuse.
// ---------------------------------------------------------------------------
__global__ __launch_bounds__(256, 2)
void gemm_k_pre_kernel(const unsigned short* __restrict__ xh, const unsigned short* __restrict__ xl,
                       const unsigned short* __restrict__ wh, const unsigned short* __restrict__ wl,
                       unsigned int* __restrict__ kout){
  __shared__ unsigned short Ah[128*40], Al[128*40];   // stride 40 shorts (pad)
  __shared__ unsigned short Bh[128*48], Bl[128*48];   // stride 48 shorts (pad)
  const int tid  = threadIdx.x;
  const int bn   = blockIdx.x;   // 0..5
  const int bm   = blockIdx.y;   // 0..511
  const int wave = tid >> 6, lane = tid & 63, quad = lane >> 4, l16 = lane & 15;
  const int wm   = (wave >> 1)*64, wn = (wave & 1)*64;

  float4v acc[4][4];
  #pragma unroll
  for(int i=0;i<4;i++)
    #pragma unroll
    for(int j=0;j<4;j++) acc[i][j] = (float4v){0.f,0.f,0.f,0.f};

  const unsigned short* xAh = xh + (size_t)bm*128*768;
  const unsigned short* xAl = xl + (size_t)bm*128*768;
  const unsigned short* wBh = wh + (size_t)bn*128*768;
  const unsigned short* wBl = wl + (size_t)bn*128*768;

  for(int k0=0;k0<768;k0+=32){
    __syncthreads();
    // stage A (128x32 bf16 hi/lo, pure copy)
    #pragma unroll
    for(int i=0;i<2;i++){
      int fi = tid + i*256;          // 0..511
      int row = fi >> 2, c8 = fi & 3;
      size_t go = (size_t)row*768 + k0 + c8*8;
      *(short8v*)(Ah + row*40 + c8*8) = *(const short8v*)(xAh + go);
      *(short8v*)(Al + row*40 + c8*8) = *(const short8v*)(xAl + go);
    }
    // stage B (128x32 bf16 hi/lo, pure copy)
    #pragma unroll
    for(int i=0;i<2;i++){
      int ci = tid + i*256;          // 0..511
      int row = ci >> 2, c8 = ci & 3;
      size_t go = (size_t)row*768 + k0 + c8*8;
      *(short8v*)(Bh + row*48 + c8*8) = *(const short8v*)(wBh + go);
      *(short8v*)(Bl + row*48 + c8*8) = *(const short8v*)(wBl + go);
    }
    __syncthreads();

    bf16x8 a_h[4], a_l[4], b_h[4], b_l[4];
    #pragma unroll
    for(int i=0;i<4;i++){
      int ar = wm + i*16 + l16;
      a_h[i] = *(const bf16x8*)(Ah + ar*40 + quad*8);
      a_l[i] = *(const bf16x8*)(Al + ar*40 + quad*8);
      int br = wn + i*16 + l16;
      b_h[i] = *(const bf16x8*)(Bh + br*48 + quad*8);
      b_l[i] = *(const bf16x8*)(Bl + br*48 + quad*8);
    }
    #pragma unroll
    for(int i=0;i<4;i++)
      #pragma unroll
      for(int j=0;j<4;j++){
        acc[i][j] = __builtin_amdgcn_mfma_f32_16x16x32_bf16(a_h[i], b_h[j], acc[i][j],0,0,0);
        acc[i][j] = __builtin_amdgcn_mfma_f32_16x16x32_bf16(a_l[i], b_h[j], acc[i][j],0,0,0);
        acc[i][j] = __builtin_amdgcn_mfma_f32_16x16x32_bf16(a_h[i], b_l[j], acc[i][j],0,0,0);
      }
  }
  const size_t cbase = (size_t)(bm*128)*768 + (size_t)bn*128;
  #pragma unroll
  for(int i=0;i<4;i++)
    #pragma unroll
    for(int j=0;j<4;j++)
      #pragma unroll
      for(int r=0;r<4;r++)
        kout[cbase + (size_t)(wm + i*16 + quad*4 + r)*768 + wn + j*16 + l16] = packbf(acc[i][j][r]);
}

// ---------------------------------------------------------------------------
// Fallback gemm (on-the-fly x conversion) — used if ws_size is too small for
// the preconverted-x buffers. Same math, packed-k output, transposed grid.
// ---------------------------------------------------------------------------
__global__ __launch_bounds__(256, 2)
void gemm_k_fly_kernel(const float* __restrict__ x, const unsigned short* __restrict__ wh,
                       const unsigned short* __restrict__ wl, unsigned int* __restrict__ kout){
  __shared__ unsigned short Ah[128*40], Al[128*40];
  __shared__ unsigned short Bh[128*48], Bl[128*48];
  const int tid  = threadIdx.x;
  const int bn   = blockIdx.x;
  const int bm   = blockIdx.y;
  const int wave = tid >> 6, lane = tid & 63, quad = lane >> 4, l16 = lane & 15;
  const int wm   = (wave >> 1)*64, wn = (wave & 1)*64;

  float4v acc[4][4];
  #pragma unroll
  for(int i=0;i<4;i++)
    #pragma unroll
    for(int j=0;j<4;j++) acc[i][j] = (float4v){0.f,0.f,0.f,0.f};

  const float* xA = x + (size_t)bm*128*768;
  const unsigned short* wBh = wh + (size_t)bn*128*768;
  const unsigned short* wBl = wl + (size_t)bn*128*768;

  for(int k0=0;k0<768;k0+=32){
    __syncthreads();
    #pragma unroll
    for(int i=0;i<4;i++){
      int fi = tid + i*256;
      int row = fi >> 3, c4 = fi & 7;
      float4v va = *(const float4v*)(xA + (size_t)row*768 + k0 + c4*4);
      short4v ha, la;
      #pragma unroll
      for(int e=0;e<4;e++){
        unsigned short hh = f2bf_hi(va[e]);
        ha[e] = (short)hh;
        la[e] = (short)f2bf_hi(va[e] - bf2f(hh));
      }
      *(short4v*)(Ah + row*40 + c4*4) = ha;
      *(short4v*)(Al + row*40 + c4*4) = la;
    }
    #pragma unroll
    for(int i=0;i<2;i++){
      int ci = tid + i*256;
      int row = ci >> 2, c8 = ci & 3;
      size_t go = (size_t)row*768 + k0 + c8*8;
      *(short8v*)(Bh + row*48 + c8*8) = *(const short8v*)(wBh + go);
      *(short8v*)(Bl + row*48 + c8*8) = *(const short8v*)(wBl + go);
    }
    __syncthreads();

    bf16x8 a_h[4], a_l[4], b_h[4], b_l[4];
    #pragma unroll
    for(int i=0;i<4;i++){
      int ar = wm + i*16 + l16;
      a_h[i] = *(const bf16x8*)(Ah + ar*40 + quad*8);
      a_l[i] = *(const bf16x8*)(Al + ar*40 + quad*8);
      int br = wn + i*16 + l16;
      b_h[i] = *(const bf16x8*)(Bh + br*48 + quad*8);
      b_l[i] = *(const bf16x8*)(Bl + br*48 + quad*8);
    }
    #pragma unroll
    for(int i=0;i<4;i++)
      #pragma unroll
      for(int j=0;j<4;j++){
        acc[i][j] = __builtin_amdgcn_mfma_f32_16x16x32_bf16(a_h[i], b_h[j], acc[i][j],0,0,0);
        acc[i][j] = __builtin_amdgcn_mfma_f32_16x16x32_bf16(a_l[i], b_h[j], acc[i][j],0,0,0);
        acc[i][j] = __builtin_amdgcn_mfma_f32_16x16x32_bf16(a_h[i], b_l[j], acc[i][j],0,0,0);
      }
  }
  const size_t cbase = (size_t)(bm*128)*768 + (size_t)bn*128;
  #pragma unroll
  for(int i=0;i<4;i++)
    #pragma unroll
    for(int j=0;j<4;j++)
      #pragma unroll
      for(int r=0;r<4;r++)
        kout[cbase + (size_t)(wm + i*16 + quad*4 + r)*768 + wn + j*16 + l16] = packbf(acc[i][j][r]);
}

// ---------------------------------------------------------------------------
// Attention step: one Hopfield iteration, split over NC n-chunks.
// k arrives PACKED (hi | lo<<16) -> staging is pure copy (no conversion VALU).
// ---------------------------------------------------------------------------
__global__ __launch_bounds__(256, 4)
void attn_step_kernel(const unsigned int* __restrict__ kbuf, const float* __restrict__ qsrc,
                      long qb_stride, float* __restrict__ qacc, float* __restrict__ lacc){
  __shared__ unsigned int knd[64*68];   // packed, [n][d], stride 68 words
  __shared__ unsigned int kdn[64*65];   // packed, [d][n], stride 65 words
  __shared__ float p_s[16*68];          // P tile fp32, stride 68
  __shared__ float red[4][16];

  const int tid  = threadIdx.x;
  const int c    = blockIdx.x;          // 0..NC-1
  const int h    = blockIdx.y;          // 0..11
  const int b    = blockIdx.z;          // 0..15
  const int wave = tid >> 6, lane = tid & 63, quad = lane >> 4, l16 = lane & 15;

  const unsigned int* kb = kbuf + ((size_t)b*4096 + (size_t)c*(4096/NC))*768 + h*64;

  // q fragments (scale 1/8 folded), split hi/lo. lane l16 = l.
  const float* qp = qsrc + (size_t)b*qb_stride + (size_t)l16*768 + h*64;
  bf16x8 qh[2], ql[2];
  #pragma unroll
  for(int s = 0; s < 2; ++s){
    float4v v0 = *(const float4v*)(qp + s*32 + quad*8);
    float4v v1 = *(const float4v*)(qp + s*32 + quad*8 + 4);
    #pragma unroll
    for(int e = 0; e < 8; ++e){
      float v = (e < 4 ? v0[e] : v1[e-4]) * 0.125f;
      unsigned short hh = f2bf_hi(v);
      qh[s][e] = (short)hh;
      ql[s][e] = (short)f2bf_hi(v - bf2f(hh));
    }
  }

  float4v acc = (float4v){0.f,0.f,0.f,0.f};
  float lsum = 0.f;

  const int sn = tid >> 2;   // staging: tile row 0..63
  const int dq = tid & 3;    // staging: 16-d group

  for(int t = 0; t < (4096/NC)/64; ++t){
    // ---- stage 64x64 packed k tile, both layouts (pure copy) ----
    const unsigned int* src = kb + (size_t)(t*64 + sn)*768 + dq*16;
    #pragma unroll
    for(int g = 0; g < 4; ++g){
      uint4v pk = *(const uint4v*)(src + g*4);
      *(uint4v*)(knd + sn*68 + dq*16 + g*4) = pk;
      const int dbase = dq*16 + g*4;
      kdn[(dbase+0)*65 + sn] = pk[0];
      kdn[(dbase+1)*65 + sn] = pk[1];
      kdn[(dbase+2)*65 + sn] = pk[2];
      kdn[(dbase+3)*65 + sn] = pk[3];
    }
    __syncthreads();                                   // S1: tile staged

    // ---- QK^T transposed: sT[n'][l]; wave w owns n' in [16w, 16w+16) ----
    float4v sfr = (float4v){0.f,0.f,0.f,0.f};
    #pragma unroll
    for(int s = 0; s < 2; ++s){
      const unsigned int* ap = knd + (wave*16 + l16)*68 + s*32 + quad*8;
      uint4v w0 = *(const uint4v*)ap;
      uint4v w1 = *(const uint4v*)(ap + 4);
      bf16x8 a_h, a_l;
      #pragma unroll
      for(int j = 0; j < 4; ++j){
        a_h[j]   = (short)(w0[j] & 0xffffu);  a_l[j]   = (short)(w0[j] >> 16);
        a_h[j+4] = (short)(w1[j] & 0xffffu);  a_l[j+4] = (short)(w1[j] >> 16);
      }
      sfr = __builtin_amdgcn_mfma_f32_16x16x32_bf16(a_h, qh[s], sfr, 0,0,0);
      sfr = __builtin_amdgcn_mfma_f32_16x16x32_bf16(a_l, qh[s], sfr, 0,0,0);
      sfr = __builtin_amdgcn_mfma_f32_16x16x32_bf16(a_h, ql[s], sfr, 0,0,0);
    }
    // sfr[r]: logit(l=l16, n_local = wave*16 + quad*4 + r)
    float4v p;
    #pragma unroll
    for(int r = 0; r < 4; ++r) p[r] = __expf(sfr[r]);
    lsum += p[0] + p[1] + p[2] + p[3];
    *(float4v*)(p_s + l16*68 + wave*16 + quad*4) = p;
    __syncthreads();                                   // S2: p_s ready

    // ---- PV: acc[l][d] += P[l][n] k[n][d]; wave w owns d in [16w,16w+16) ----
    #pragma unroll
    for(int s = 0; s < 2; ++s){
      const float* pp = p_s + l16*68 + s*32 + quad*8;
      float4v p0 = *(const float4v*)pp;
      float4v p1 = *(const float4v*)(pp + 4);
      bf16x8 pa_h, pa_l;
      #pragma unroll
      for(int e = 0; e < 8; ++e){
        float v = (e < 4 ? p0[e] : p1[e-4]);
        unsigned short hh = f2bf_hi(v);
        pa_h[e] = (short)hh;
        pa_l[e] = (short)f2bf_hi(v - bf2f(hh));
      }
      const unsigned int* bp = kdn + (wave*16 + l16)*65 + s*32 + quad*8;
      bf16x8 kb_h, kb_l;
      #pragma unroll
      for(int j = 0; j < 8; ++j){
        unsigned int w = bp[j];
        kb_h[j] = (short)(w & 0xffffu);
        kb_l[j] = (short)(w >> 16);
      }
      acc = __builtin_amdgcn_mfma_f32_16x16x32_bf16(pa_h, kb_h, acc, 0,0,0);
      acc = __builtin_amdgcn_mfma_f32_16x16x32_bf16(pa_l, kb_h, acc, 0,0,0);
      acc = __builtin_amdgcn_mfma_f32_16x16x32_bf16(pa_h, kb_l, acc, 0,0,0);
    }
    __syncthreads();                                   // S3: done with tile LDS
  }

  // ---- epilogue: reduce lsum per l, atomic partials ----
  lsum += __shfl_xor(lsum, 16);
  lsum += __shfl_xor(lsum, 32);
  if(quad == 0) red[wave][l16] = lsum;
  __syncthreads();
  if(tid < 16){
    float tot = red[0][tid] + red[1][tid] + red[2][tid] + red[3][tid];
    atomicAdd(&lacc[(b*12 + h)*16 + tid], tot);
  }
  #pragma unroll
  for(int r = 0; r < 4; ++r){
    atomicAdd(&qacc[(size_t)(b*16 + quad*4 + r)*768 + h*64 + wave*16 + l16], acc[r]);
  }
}

// ---------------------------------------------------------------------------
// Normalize: qcur = qacc / (1 + lacc); then zero qacc/lacc for the next step.
// ---------------------------------------------------------------------------
__global__ __launch_bounds__(256)
void attn_norm_kernel(float* __restrict__ qacc, float* __restrict__ lacc,
                      float* __restrict__ qcur){
  __shared__ float lt[16];
  const int bh = blockIdx.x, b = bh/12, h = bh - (bh/12)*12, tid = threadIdx.x;
  if(tid < 16) lt[tid] = 1.f + lacc[bh*16 + tid];
  __syncthreads();
  if(tid < 16) lacc[bh*16 + tid] = 0.f;
  for(int idx = tid; idx < 1024; idx += 256){
    int l = idx >> 6, d = idx & 63;
    size_t a = (size_t)(b*16 + l)*768 + h*64 + d;
    qcur[a] = qacc[a] / lt[l];
    qacc[a] = 0.f;
  }
}

// ---------------------------------------------------------------------------
// out[r][c] = sum_j inp[r][j]*W[c][j] (+bias). 4 rows x 256 cols per block.
// ---------------------------------------------------------------------------
__global__ __launch_bounds__(256)
void proj_kernel(const float* __restrict__ inp, const float* __restrict__ w,
                 const float* __restrict__ bias, float* __restrict__ out){
  __shared__ float rows[4*768];
  const int r0 = blockIdx.x*4;
  const int c  = blockIdx.y*256 + threadIdx.x;
  for(int j = threadIdx.x; j < 4*768; j += 256) rows[j] = inp[(size_t)r0*768 + j];
  __syncthreads();
  const float* wr = w + (size_t)c*768;
  float a0=0.f, a1=0.f, a2=0.f, a3=0.f;
  for(int j=0;j<768;j+=4){
    float4v w4 = *(const float4v*)(wr+j);
    float4v r0v = *(const float4v*)(rows+j);
    float4v r1v = *(const float4v*)(rows+768+j);
    float4v r2v = *(const float4v*)(rows+1536+j);
    float4v r3v = *(const float4v*)(rows+2304+j);
    #pragma unroll
    for(int e=0;e<4;e++){
      a0 += r0v[e]*w4[e]; a1 += r1v[e]*w4[e];
      a2 += r2v[e]*w4[e]; a3 += r3v[e]*w4[e];
    }
  }
  const float bb = bias ? bias[c] : 0.f;
  out[(size_t)(r0+0)*768 + c] = a0 + bb;
  out[(size_t)(r0+1)*768 + c] = a1 + bb;
  out[(size_t)(r0+2)*768 + c] = a2 + bb;
  out[(size_t)(r0+3)*768 + c] = a3 + bb;
}

// ---------------------------------------------------------------------------
extern "C" void kernel_launch(void* const* d_in, const int* in_sizes, int n_in,
                              void* d_out, int out_size, void* d_ws, size_t ws_size,
                              hipStream_t stream){
  const float* x     = (const float*)d_in[0];   // [16,4096,768]
  const float* query = (const float*)d_in[1];   // [1,16,768]
  const float* Wq    = (const float*)d_in[2];   // [768,768]
  const float* Wk    = (const float*)d_in[3];
  const float* Wv    = (const float*)d_in[4];
  const float* Wproj = (const float*)d_in[5];
  const float* bproj = (const float*)d_in[6];   // [768]
  float* out = (float*)d_out;                   // [16,16,768] fp32

  const size_t XB   = 100663296;   // xh / xl bytes (bf16 plane of x)
  const size_t KB_  = 201326592;   // packed k bytes
  const size_t PRE_NEED = 2*XB + KB_ + 786432 + 49152 + 2359296;  // ~387 MB

  char* ws = (char*)d_ws;
  if(ws_size >= PRE_NEED){
    // ---- preconverted-x path ----
    unsigned short* xh   = (unsigned short*)(ws);
    unsigned short* xl   = (unsigned short*)(ws + XB);
    unsigned int*   kbuf = (unsigned int*)  (ws + 2*XB);
    float*          qcur = (float*)(ws + 2*XB + KB_);
    float*          q0   = (float*)(ws + 2*XB + KB_ + 786432);
    char*           R    = ws + 2*XB + KB_ + 786432 + 49152;
    unsigned short* wkh  = (unsigned short*)(R);
    unsigned short* wkl  = (unsigned short*)(R + 1179648);
    float*          qacc = (float*)(R);          // alias after gemm
    float*          lacc = (float*)(R + 786432);
    float*          out1 = (float*)(R);          // alias in proj phase

    cvt_planar_kernel<<<576, 256, 0, stream>>>(Wk, wkh, wkl);
    cvt_planar_kernel<<<49152, 256, 0, stream>>>(x, xh, xl);
    q0_kernel<<<48, 256, 0, stream>>>(query, Wq, q0);
    gemm_k_pre_kernel<<<dim3(6, 512), 256, 0, stream>>>(xh, xl, wkh, wkl, kbuf);

    hipMemsetAsync(qacc, 0, 786432 + 12288, stream);
    dim3 sg(NC, 12, 16);
    attn_step_kernel<<<sg, 256, 0, stream>>>(kbuf, q0,   0,       qacc, lacc);
    attn_norm_kernel<<<192, 256, 0, stream>>>(qacc, lacc, qcur);
    attn_step_kernel<<<sg, 256, 0, stream>>>(kbuf, qcur, 16*768,  qacc, lacc);
    attn_norm_kernel<<<192, 256, 0, stream>>>(qacc, lacc, qcur);
    attn_step_kernel<<<sg, 256, 0, stream>>>(kbuf, qcur, 16*768,  qacc, lacc);
    attn_norm_kernel<<<192, 256, 0, stream>>>(qacc, lacc, qcur);

    proj_kernel<<<dim3(64, 3), 256, 0, stream>>>(qcur, Wv, nullptr, out1);
    proj_kernel<<<dim3(64, 3), 256, 0, stream>>>(out1, Wproj, bproj, out);
  } else {
    // ---- fallback: on-the-fly x conversion (round-2 layout) ----
    unsigned int*   kbuf = (unsigned int*)(ws);            // 201326592 B
    float*          qcur = (float*)(ws + 201326592);       // 786432 B
    float*          q0   = (float*)(ws + 202113024);       // 49152 B
    char*           R    = ws + 202162176;                 // 2359296 B region
    unsigned short* wkh  = (unsigned short*)(R);
    unsigned short* wkl  = (unsigned short*)(R + 1179648);
    float*          qacc = (float*)(R);
    float*          lacc = (float*)(R + 786432);
    float*          out1 = (float*)(R);

    cvt_planar_kernel<<<576, 256, 0, stream>>>(Wk, wkh, wkl);
    q0_kernel<<<48, 256, 0, stream>>>(query, Wq, q0);
    gemm_k_fly_kernel<<<dim3(6, 512), 256, 0, stream>>>(x, wkh, wkl, kbuf);

    hipMemsetAsync(qacc, 0, 786432 + 12288, stream);
    dim3 sg(NC, 12, 16);
    attn_step_kernel<<<sg, 256, 0, stream>>>(kbuf, q0,   0,       qacc, lacc);
    attn_norm_kernel<<<192, 256, 0, stream>>>(qacc, lacc, qcur);
    attn_step_kernel<<<sg, 256, 0, stream>>>(kbuf, qcur, 16*768,  qacc, lacc);
    attn_norm_kernel<<<192, 256, 0, stream>>>(qacc, lacc, qcur);
    attn_step_kernel<<<sg, 256, 0, stream>>>(kbuf, qcur, 16*768,  qacc, lacc);
    attn_norm_kernel<<<192, 256, 0, stream>>>(qacc, lacc, qcur);

    proj_kernel<<<dim3(64, 3), 256, 0, stream>>>(qcur, Wv, nullptr, out1);
    proj_kernel<<<dim3(64, 3), 256, 0, stream>>>(out1, Wproj, bproj, out);
  }
}

// Round 4
// 742.224 us; speedup vs baseline: 1.1331x; 1.1331x over previous
//
#include <hip/hip_runtime.h>

// ---------------------------------------------------------------------------
// HopfieldPooling on MI355X (gfx950)
//   k = x@Wk^T  (split-bf16 MFMA, 3-term; A via LDS w/ on-stage convert,
//                B register-direct from L2-resident W planes; XCD swizzle)
//   q0 = query@Wq^T (fp32)
//   3x Hopfield steps: split-N attention, fixed shift m=0 (softmax_1), atomics
//   out = (q@Wv^T)@Wproj^T + b  (fp32 vector)
// ---------------------------------------------------------------------------

typedef float  float4v  __attribute__((ext_vector_type(4)));
typedef short  short4v  __attribute__((ext_vector_type(4)));
typedef short  short8v  __attribute__((ext_vector_type(8)));
typedef unsigned int uint4v __attribute__((ext_vector_type(4)));
typedef short8v bf16x8;   // 8 bf16 = 4 VGPRs, MFMA A/B frag

#define NC 16   // n-chunks per (b,h) in attention step

__device__ __forceinline__ unsigned short f2bf_hi(float f){
  unsigned int u = __float_as_uint(f);
  u += 0x7fffu + ((u >> 16) & 1u);            // round-to-nearest-even
  return (unsigned short)(u >> 16);
}
__device__ __forceinline__ float bf2f(unsigned short h){
  return __uint_as_float(((unsigned int)h) << 16);
}
__device__ __forceinline__ unsigned int packbf(float v){
  unsigned short hh = f2bf_hi(v);
  return (unsigned)hh | ((unsigned)f2bf_hi(v - bf2f(hh)) << 16);
}

// ---------------------------------------------------------------------------
// fp32 -> planar hi/lo bf16 (Wk 768x768)
// ---------------------------------------------------------------------------
__global__ __launch_bounds__(256)
void cvt_planar_kernel(const float* __restrict__ src, unsigned short* __restrict__ dh,
                       unsigned short* __restrict__ dl){
  size_t idx = (size_t)blockIdx.x*256 + threadIdx.x;
  float4v v = ((const float4v*)src)[idx];
  short4v h4, l4;
  #pragma unroll
  for(int e=0;e<4;e++){
    unsigned short hh = f2bf_hi(v[e]);
    h4[e] = (short)hh;
    l4[e] = (short)f2bf_hi(v[e] - bf2f(hh));
  }
  ((short4v*)dh)[idx] = h4;
  ((short4v*)dl)[idx] = l4;
}

// ---------------------------------------------------------------------------
// q0[l][c] = sum_j query[l][j]*Wq[c][j]   (16x768, fp32)
// ---------------------------------------------------------------------------
__global__ __launch_bounds__(256)
void q0_kernel(const float* __restrict__ query, const float* __restrict__ wq,
               float* __restrict__ q0){
  int idx = blockIdx.x*256 + threadIdx.x;     // 12288
  int l = idx / 768, c = idx - l*768;
  const float* qr = query + l*768;
  const float* wr = wq + (size_t)c*768;
  float s = 0.f;
  for(int j=0;j<768;j+=4){
    float4v a  = *(const float4v*)(qr+j);
    float4v w4 = *(const float4v*)(wr+j);
    s += a[0]*w4[0]+a[1]*w4[1]+a[2]*w4[2]+a[3]*w4[3];
  }
  q0[idx] = s;
}

// ---------------------------------------------------------------------------
// k = x @ Wk^T : M=65536, N=768, K=768. Block tile 128x128, BK=32, 4 waves.
// Wave tile = 128 rows x 32 cols: A shared via LDS (on-stage fp32->hi/lo
// convert), B frags loaded register-direct from global W planes (L2-hot,
// no cross-wave duplication, no barrier dependency -> pipelines across k0).
// 1D grid, XCD swizzle: all 6 bn-blocks of a bm on the same XCD.
// Output k packed (hi | lo<<16).
// ---------------------------------------------------------------------------
__global__ __launch_bounds__(256, 3)
void gemm_k_kernel(const float* __restrict__ x, const unsigned short* __restrict__ wh,
                   const unsigned short* __restrict__ wl, unsigned int* __restrict__ kout){
  __shared__ unsigned short Ah[128*40], Al[128*40];   // stride 40 shorts
  const int tid  = threadIdx.x;
  const int id   = blockIdx.x;          // 0..3071
  const int xcd  = id & 7, slot = id >> 3;
  const int bml  = slot / 6;            // 0..63
  const int bn   = slot - bml*6;        // 0..5
  const int bm   = xcd*64 + bml;        // 0..511
  const int wave = tid >> 6, lane = tid & 63, quad = lane >> 4, l16 = lane & 15;

  float4v acc[8][2];
  #pragma unroll
  for(int i=0;i<8;i++)
    #pragma unroll
    for(int j=0;j<2;j++) acc[i][j] = (float4v){0.f,0.f,0.f,0.f};

  const float* xA = x + (size_t)bm*128*768;
  // this wave's B rows (output cols): bn*128 + wave*32 + j*16 + l16
  const unsigned short* wbh = wh + (size_t)(bn*128 + wave*32 + l16)*768 + quad*8;
  const unsigned short* wbl = wl + (size_t)(bn*128 + wave*32 + l16)*768 + quad*8;

  for(int k0=0;k0<768;k0+=32){
    // B frags register-direct (global, L2-resident; no barrier dependency)
    bf16x8 b_h[2], b_l[2];
    #pragma unroll
    for(int j=0;j<2;j++){
      b_h[j] = *(const bf16x8*)(wbh + (size_t)j*16*768 + k0);
      b_l[j] = *(const bf16x8*)(wbl + (size_t)j*16*768 + k0);
    }
    __syncthreads();
    // stage A (128x32 fp32 -> hi/lo), 8 k-elems per thread, b128 writes
    #pragma unroll
    for(int i=0;i<2;i++){
      int fi = tid + i*256;          // 0..511
      int row = fi >> 2, c8 = fi & 3;
      const float* sp = xA + (size_t)row*768 + k0 + c8*8;
      float4v va = *(const float4v*)sp;
      float4v vb = *(const float4v*)(sp + 4);
      short8v hv, lv;
      #pragma unroll
      for(int e=0;e<4;e++){
        unsigned short hh = f2bf_hi(va[e]);
        hv[e] = (short)hh; lv[e] = (short)f2bf_hi(va[e] - bf2f(hh));
        unsigned short hh2 = f2bf_hi(vb[e]);
        hv[e+4] = (short)hh2; lv[e+4] = (short)f2bf_hi(vb[e] - bf2f(hh2));
      }
      *(short8v*)(Ah + row*40 + c8*8) = hv;
      *(short8v*)(Al + row*40 + c8*8) = lv;
    }
    __syncthreads();

    #pragma unroll
    for(int i=0;i<8;i++){
      const int ar = i*16 + l16;
      bf16x8 a_h = *(const bf16x8*)(Ah + ar*40 + quad*8);
      bf16x8 a_l = *(const bf16x8*)(Al + ar*40 + quad*8);
      #pragma unroll
      for(int j=0;j<2;j++){
        acc[i][j] = __builtin_amdgcn_mfma_f32_16x16x32_bf16(a_h, b_h[j], acc[i][j],0,0,0);
        acc[i][j] = __builtin_amdgcn_mfma_f32_16x16x32_bf16(a_l, b_h[j], acc[i][j],0,0,0);
        acc[i][j] = __builtin_amdgcn_mfma_f32_16x16x32_bf16(a_h, b_l[j], acc[i][j],0,0,0);
      }
    }
  }
  // epilogue: D row=(i*16+quad*4+r), col=(wave*32+j*16+l16); packed store
  const size_t cbase = (size_t)(bm*128)*768 + bn*128 + wave*32;
  #pragma unroll
  for(int i=0;i<8;i++)
    #pragma unroll
    for(int j=0;j<2;j++)
      #pragma unroll
      for(int r=0;r<4;r++)
        kout[cbase + (size_t)(i*16 + quad*4 + r)*768 + j*16 + l16] = packbf(acc[i][j][r]);
}

// ---------------------------------------------------------------------------
// Attention step: one Hopfield iteration, split over NC n-chunks.
// k arrives PACKED (hi | lo<<16). Single [n][d] LDS tile; PV B-frags read
// strided from knd (4-way bank conflict, traded for -17KB LDS + occupancy).
// ---------------------------------------------------------------------------
__global__ __launch_bounds__(256, 6)
void attn_step_kernel(const unsigned int* __restrict__ kbuf, const float* __restrict__ qsrc,
                      long qb_stride, float* __restrict__ qacc, float* __restrict__ lacc){
  __shared__ unsigned int knd[64*68];   // packed, [n][d], stride 68 words
  __shared__ float p_s[16*68];          // P tile fp32, stride 68
  __shared__ float red[4][16];

  const int tid  = threadIdx.x;
  const int c    = blockIdx.x;          // 0..NC-1
  const int h    = blockIdx.y;          // 0..11
  const int b    = blockIdx.z;          // 0..15
  const int wave = tid >> 6, lane = tid & 63, quad = lane >> 4, l16 = lane & 15;

  const unsigned int* kb = kbuf + ((size_t)b*4096 + (size_t)c*(4096/NC))*768 + h*64;

  // q fragments (scale 1/8 folded), split hi/lo. lane l16 = l.
  const float* qp = qsrc + (size_t)b*qb_stride + (size_t)l16*768 + h*64;
  bf16x8 qh[2], ql[2];
  #pragma unroll
  for(int s = 0; s < 2; ++s){
    float4v v0 = *(const float4v*)(qp + s*32 + quad*8);
    float4v v1 = *(const float4v*)(qp + s*32 + quad*8 + 4);
    #pragma unroll
    for(int e = 0; e < 8; ++e){
      float v = (e < 4 ? v0[e] : v1[e-4]) * 0.125f;
      unsigned short hh = f2bf_hi(v);
      qh[s][e] = (short)hh;
      ql[s][e] = (short)f2bf_hi(v - bf2f(hh));
    }
  }

  float4v acc = (float4v){0.f,0.f,0.f,0.f};
  float lsum = 0.f;

  const int sn = tid >> 2;   // staging: tile row 0..63
  const int dq = tid & 3;    // staging: 16-d group

  for(int t = 0; t < (4096/NC)/64; ++t){
    // ---- stage 64x64 packed k tile (pure copy, b128) ----
    const unsigned int* src = kb + (size_t)(t*64 + sn)*768 + dq*16;
    #pragma unroll
    for(int g = 0; g < 4; ++g){
      *(uint4v*)(knd + sn*68 + dq*16 + g*4) = *(const uint4v*)(src + g*4);
    }
    __syncthreads();                                   // S1: tile staged

    // ---- QK^T transposed: sT[n'][l]; wave w owns n' in [16w, 16w+16) ----
    float4v sfr = (float4v){0.f,0.f,0.f,0.f};
    #pragma unroll
    for(int s = 0; s < 2; ++s){
      const unsigned int* ap = knd + (wave*16 + l16)*68 + s*32 + quad*8;
      uint4v w0 = *(const uint4v*)ap;
      uint4v w1 = *(const uint4v*)(ap + 4);
      bf16x8 a_h, a_l;
      #pragma unroll
      for(int j = 0; j < 4; ++j){
        a_h[j]   = (short)(w0[j] & 0xffffu);  a_l[j]   = (short)(w0[j] >> 16);
        a_h[j+4] = (short)(w1[j] & 0xffffu);  a_l[j+4] = (short)(w1[j] >> 16);
      }
      sfr = __builtin_amdgcn_mfma_f32_16x16x32_bf16(a_h, qh[s], sfr, 0,0,0);
      sfr = __builtin_amdgcn_mfma_f32_16x16x32_bf16(a_l, qh[s], sfr, 0,0,0);
      sfr = __builtin_amdgcn_mfma_f32_16x16x32_bf16(a_h, ql[s], sfr, 0,0,0);
    }
    // sfr[r]: logit(l=l16, n_local = wave*16 + quad*4 + r)
    float4v p;
    #pragma unroll
    for(int r = 0; r < 4; ++r) p[r] = __expf(sfr[r]);
    lsum += p[0] + p[1] + p[2] + p[3];
    *(float4v*)(p_s + l16*68 + wave*16 + quad*4) = p;
    __syncthreads();                                   // S2: p_s ready

    // ---- PV: acc[l][d] += P[l][n] k[n][d]; wave w owns d in [16w,16w+16) ----
    #pragma unroll
    for(int s = 0; s < 2; ++s){
      const float* pp = p_s + l16*68 + s*32 + quad*8;
      float4v p0 = *(const float4v*)pp;
      float4v p1 = *(const float4v*)(pp + 4);
      bf16x8 pa_h, pa_l;
      #pragma unroll
      for(int e = 0; e < 8; ++e){
        float v = (e < 4 ? p0[e] : p1[e-4]);
        unsigned short hh = f2bf_hi(v);
        pa_h[e] = (short)hh;
        pa_l[e] = (short)f2bf_hi(v - bf2f(hh));
      }
      // B-frag: k[n = s*32+quad*8+j][d = wave*16+l16], strided reads from knd
      const unsigned int* bp = knd + (size_t)(s*32 + quad*8)*68 + wave*16 + l16;
      bf16x8 kb_h, kb_l;
      #pragma unroll
      for(int j = 0; j < 8; ++j){
        unsigned int w = bp[j*68];
        kb_h[j] = (short)(w & 0xffffu);
        kb_l[j] = (short)(w >> 16);
      }
      acc = __builtin_amdgcn_mfma_f32_16x16x32_bf16(pa_h, kb_h, acc, 0,0,0);
      acc = __builtin_amdgcn_mfma_f32_16x16x32_bf16(pa_l, kb_h, acc, 0,0,0);
      acc = __builtin_amdgcn_mfma_f32_16x16x32_bf16(pa_h, kb_l, acc, 0,0,0);
    }
    __syncthreads();                                   // S3: done with tile LDS
  }

  // ---- epilogue: reduce lsum per l, atomic partials ----
  lsum += __shfl_xor(lsum, 16);
  lsum += __shfl_xor(lsum, 32);
  if(quad == 0) red[wave][l16] = lsum;
  __syncthreads();
  if(tid < 16){
    float tot = red[0][tid] + red[1][tid] + red[2][tid] + red[3][tid];
    atomicAdd(&lacc[(b*12 + h)*16 + tid], tot);
  }
  #pragma unroll
  for(int r = 0; r < 4; ++r){
    atomicAdd(&qacc[(size_t)(b*16 + quad*4 + r)*768 + h*64 + wave*16 + l16], acc[r]);
  }
}

// ---------------------------------------------------------------------------
// Normalize: qcur = qacc / (1 + lacc); then zero qacc/lacc for the next step.
// ---------------------------------------------------------------------------
__global__ __launch_bounds__(256)
void attn_norm_kernel(float* __restrict__ qacc, float* __restrict__ lacc,
                      float* __restrict__ qcur){
  __shared__ float lt[16];
  const int bh = blockIdx.x, b = bh/12, h = bh - (bh/12)*12, tid = threadIdx.x;
  if(tid < 16) lt[tid] = 1.f + lacc[bh*16 + tid];
  __syncthreads();
  if(tid < 16) lacc[bh*16 + tid] = 0.f;
  for(int idx = tid; idx < 1024; idx += 256){
    int l = idx >> 6, d = idx & 63;
    size_t a = (size_t)(b*16 + l)*768 + h*64 + d;
    qcur[a] = qacc[a] / lt[l];
    qacc[a] = 0.f;
  }
}

// ---------------------------------------------------------------------------
// out[r][c] = sum_j inp[r][j]*W[c][j] (+bias). 4 rows x 256 cols per block.
// ---------------------------------------------------------------------------
__global__ __launch_bounds__(256)
void proj_kernel(const float* __restrict__ inp, const float* __restrict__ w,
                 const float* __restrict__ bias, float* __restrict__ out){
  __shared__ float rows[4*768];
  const int r0 = blockIdx.x*4;
  const int c  = blockIdx.y*256 + threadIdx.x;
  for(int j = threadIdx.x; j < 4*768; j += 256) rows[j] = inp[(size_t)r0*768 + j];
  __syncthreads();
  const float* wr = w + (size_t)c*768;
  float a0=0.f, a1=0.f, a2=0.f, a3=0.f;
  for(int j=0;j<768;j+=4){
    float4v w4 = *(const float4v*)(wr+j);
    float4v r0v = *(const float4v*)(rows+j);
    float4v r1v = *(const float4v*)(rows+768+j);
    float4v r2v = *(const float4v*)(rows+1536+j);
    float4v r3v = *(const float4v*)(rows+2304+j);
    #pragma unroll
    for(int e=0;e<4;e++){
      a0 += r0v[e]*w4[e]; a1 += r1v[e]*w4[e];
      a2 += r2v[e]*w4[e]; a3 += r3v[e]*w4[e];
    }
  }
  const float bb = bias ? bias[c] : 0.f;
  out[(size_t)(r0+0)*768 + c] = a0 + bb;
  out[(size_t)(r0+1)*768 + c] = a1 + bb;
  out[(size_t)(r0+2)*768 + c] = a2 + bb;
  out[(size_t)(r0+3)*768 + c] = a3 + bb;
}

// ---------------------------------------------------------------------------
extern "C" void kernel_launch(void* const* d_in, const int* in_sizes, int n_in,
                              void* d_out, int out_size, void* d_ws, size_t ws_size,
                              hipStream_t stream){
  const float* x     = (const float*)d_in[0];   // [16,4096,768]
  const float* query = (const float*)d_in[1];   // [1,16,768]
  const float* Wq    = (const float*)d_in[2];   // [768,768]
  const float* Wk    = (const float*)d_in[3];
  const float* Wv    = (const float*)d_in[4];
  const float* Wproj = (const float*)d_in[5];
  const float* bproj = (const float*)d_in[6];   // [768]
  float* out = (float*)d_out;                   // [16,16,768] fp32

  char* ws = (char*)d_ws;
  // layout (~205 MB; wk region reused as qacc/lacc, then out1)
  unsigned int*   kbuf = (unsigned int*)(ws);            // 201326592 B
  float*          qcur = (float*)(ws + 201326592);       // 786432 B
  float*          q0   = (float*)(ws + 202113024);       // 49152 B
  char*           R    = ws + 202162176;                 // 2359296 B region
  unsigned short* wkh  = (unsigned short*)(R);           // gemm phase
  unsigned short* wkl  = (unsigned short*)(R + 1179648);
  float*          qacc = (float*)(R);                    // attn phase (alias)
  float*          lacc = (float*)(R + 786432);           // 12288 B
  float*          out1 = (float*)(R);                    // proj phase (alias)

  cvt_planar_kernel<<<576, 256, 0, stream>>>(Wk, wkh, wkl);
  q0_kernel<<<48, 256, 0, stream>>>(query, Wq, q0);
  gemm_k_kernel<<<3072, 256, 0, stream>>>(x, wkh, wkl, kbuf);

  hipMemsetAsync(qacc, 0, 786432 + 12288, stream);
  dim3 sg(NC, 12, 16);
  attn_step_kernel<<<sg, 256, 0, stream>>>(kbuf, q0,   0,       qacc, lacc);
  attn_norm_kernel<<<192, 256, 0, stream>>>(qacc, lacc, qcur);
  attn_step_kernel<<<sg, 256, 0, stream>>>(kbuf, qcur, 16*768,  qacc, lacc);
  attn_norm_kernel<<<192, 256, 0, stream>>>(qacc, lacc, qcur);
  attn_step_kernel<<<sg, 256, 0, stream>>>(kbuf, qcur, 16*768,  qacc, lacc);
  attn_norm_kernel<<<192, 256, 0, stream>>>(qacc, lacc, qcur);

  proj_kernel<<<dim3(64, 3), 256, 0, stream>>>(qcur, Wv, nullptr, out1);
  proj_kernel<<<dim3(64, 3), 256, 0, stream>>>(out1, Wproj, bproj, out);
}